// Round 7
// baseline (227.100 us; speedup 1.0000x reference)
//
#include <hip/hip_runtime.h>

#define GROUPS 32
#define EPS 1e-5f

typedef unsigned short u16;
typedef __bf16 bf16x8 __attribute__((ext_vector_type(8)));
typedef float f32x4 __attribute__((ext_vector_type(4)));

__device__ __forceinline__ u16 f2bf(float f) {
  unsigned x = __builtin_bit_cast(unsigned, f);
  x += 0x7FFFu + ((x >> 16) & 1u);
  return (u16)(x >> 16);
}
__device__ __forceinline__ float bf2f(u16 u) {
  unsigned x = ((unsigned)u) << 16;
  return __builtin_bit_cast(float, x);
}

__device__ __forceinline__ void gload_lds16(const void* g, void* l) {
  __builtin_amdgcn_global_load_lds(
      (const __attribute__((address_space(1))) void*)g,
      (__attribute__((address_space(3))) void*)l, 16, 0, 0);
}

// ---------------- weight fp32 -> bf16 (all 4 weights, one dispatch) --------
__global__ __launch_bounds__(256) void cvt_kernel(
    const float* __restrict__ wq, const float* __restrict__ wk,
    const float* __restrict__ wv, const float* __restrict__ wo,
    u16* __restrict__ Wqk, u16* __restrict__ Wv, u16* __restrict__ Wo,
    int n) {
  int i = (blockIdx.x * 256 + threadIdx.x) * 4;
  if (i >= n) return;
  const float* src;
  u16* dst;
  switch (blockIdx.y) {
    case 0: src = wq; dst = Wqk; break;
    case 1: src = wk; dst = Wqk + n; break;
    case 2: src = wv; dst = Wv; break;
    default: src = wo; dst = Wo; break;
  }
  float4 v = *(const float4*)&src[i];
  ushort4 o;
  o.x = f2bf(v.x); o.y = f2bf(v.y); o.z = f2bf(v.z); o.w = f2bf(v.w);
  *(ushort4*)&dst[i] = o;
}

// ---------------- bias concat bq||bk -> fp32[1024] ----------------
__global__ __launch_bounds__(256) void biascat_kernel(
    const float* __restrict__ bq, const float* __restrict__ bk,
    float* __restrict__ bqk, int C) {
  int i = blockIdx.x * 256 + threadIdx.x;
  if (i < C) bqk[i] = bq[i];
  else if (i < 2 * C) bqk[i] = bk[i - C];
}

// ---------------- GroupNorm -> HT [N, S, C] bf16 ----------------
// Caches the 64 KB group slab in LDS during the stats pass; x is read
// from HBM exactly once.
__global__ __launch_bounds__(256) void groupnorm_kernel(
    const float* __restrict__ x, const float* __restrict__ gamma,
    const float* __restrict__ beta, u16* __restrict__ HT, int C, int S) {
  const int cpg = C / GROUPS;  // 16
  __shared__ float xs[16 * 1024];  // 64 KB, layout == global slab [c][sp]
  __shared__ float rs[4], rss[4];
  int n = blockIdx.x / GROUPS;
  int g = blockIdx.x % GROUPS;
  const float* xb = x + ((size_t)n * C + (size_t)g * cpg) * S;
  int tid = threadIdx.x;
  int cnt = cpg * S;  // 16384
  float s = 0.f, ss = 0.f;
  for (int i = tid * 4; i < cnt; i += 256 * 4) {
    float4 v = *(const float4*)&xb[i];
    *(float4*)&xs[i] = v;
    s += v.x + v.y + v.z + v.w;
    ss += v.x * v.x + v.y * v.y + v.z * v.z + v.w * v.w;
  }
  for (int o = 32; o > 0; o >>= 1) {
    s += __shfl_xor(s, o);
    ss += __shfl_xor(ss, o);
  }
  int wave = tid >> 6, lane = tid & 63;
  if (lane == 0) { rs[wave] = s; rss[wave] = ss; }
  __syncthreads();
  float S1 = rs[0] + rs[1] + rs[2] + rs[3];
  float S2 = rss[0] + rss[1] + rss[2] + rss[3];
  float mean = S1 / (float)cnt;
  float var = S2 / (float)cnt - mean * mean;
  float rstd = rsqrtf(var + EPS);
  float gm[16], bt[16];
#pragma unroll
  for (int c = 0; c < 16; ++c) {
    float gmv = gamma[g * cpg + c] * rstd;
    gm[c] = gmv;
    bt[c] = beta[g * cpg + c] - mean * gmv;
  }
  for (int i = 0; i < S; i += 256) {
    int sp = i + tid;
    u16 outv[16];
#pragma unroll
    for (int c = 0; c < 16; ++c) {
      float h = xs[c * 1024 + sp] * gm[c] + bt[c];
      outv[c] = f2bf(h);
    }
    u16* dst = HT + ((size_t)n * S + sp) * C + g * cpg;
    *(int4*)dst = *(int4*)&outv[0];
    *(int4*)&dst[8] = *(int4*)&outv[8];
  }
}

// ============ 128x128x32 GEMM, drain-free depth-3 pipeline (ring-4) ========
// Out[m][n] = scale*sum_k A[m][k]*B[n][k] (+bias/residual)
// Per step t: STAGE(t+3) into slot (t+3)&3 (== slot consumed at step t-1;
// the start-of-step barrier orders those writes after all waves' t-1 reads);
// s_waitcnt vmcnt(12) waits ONLY for stage t (12 loads from stages t+1..t+3
// stay in flight across the barrier -- never drain); s_barrier makes the
// per-wave gate collective; then ds_read slot t&3 + 16 MFMA.
// Wrap-around staging keeps outstanding==16 uniform (tail reloads a dead
// slot). 64 KB LDS -> 2 blocks/CU.
// Row = 32 bf16 = 4 x 16B slots; physical slot p holds global slot
// p ^ (r&3) ^ ((r>>2)&3)  (2 passes/quarter-wave on reads = free).
__global__ __launch_bounds__(256, 2) void gemm128_kernel(
    const u16* __restrict__ A, long lda, long strideA,
    const u16* __restrict__ B, long ldb, long strideB,
    void* __restrict__ Out, long ldo, long strideO, int out_fp32,
    const float* __restrict__ bias, int bias_mode,  // 0 none, 1 row, 2 col
    float scale, const float* __restrict__ residual, int K, int nbx, int nby) {
  __shared__ u16 lds[32768];  // 64 KiB: slot s -> A at s*8192, B at +4096

  int tid = threadIdx.x;
  int wave = tid >> 6, lane = tid & 63;
  int wr = wave >> 1, wc = wave & 1;
  int l15 = lane & 15, l4 = lane >> 4;

  int nwg = gridDim.x;
  int orig = blockIdx.x;
  int swz = ((nwg & 7) == 0) ? (orig & 7) * (nwg >> 3) + (orig >> 3) : orig;
  int tilesPB = nbx * nby;
  int z = swz / tilesPB, rem = swz % tilesPB;
  int bx = rem % nbx, by = rem / nbx;

  const u16* Ab = A + (long)z * strideA + (long)by * 128 * lda;
  const u16* Bb = B + (long)z * strideB + (long)bx * 128 * ldb;

  // stage one 128x32 tile of A and B into ring slot
  auto STAGE = [&](int slot, int kt) {
    u16* Ad = lds + slot * 8192;
    u16* Bd = Ad + 4096;
#pragma unroll
    for (int i = 0; i < 2; ++i) {
      int c = i * 256 + tid;          // 0..511 16B chunks
      int row = c >> 2, p = c & 3;
      int gsl = p ^ (row & 3) ^ ((row >> 2) & 3);  // inverse swizzle on src
      long koff = (long)kt * 32 + gsl * 8;
      int lbase = (i * 256 + wave * 64) * 8;  // wave-uniform LDS base (elems)
      gload_lds16(Ab + (long)row * lda + koff, Ad + lbase);
      gload_lds16(Bb + (long)row * ldb + koff, Bd + lbase);
    }
  };

  f32x4 acc[4][4] = {};

  auto COMPUTE = [&](const u16* Asrc, const u16* Bsrc) {
    bf16x8 af[4], bfr[4];
#pragma unroll
    for (int m = 0; m < 4; ++m) {
      int row = wr * 64 + m * 16 + l15;
      int p = l4 ^ (row & 3) ^ ((row >> 2) & 3);
      af[m] = *(const bf16x8*)&Asrc[row * 32 + p * 8];
    }
#pragma unroll
    for (int n = 0; n < 4; ++n) {
      int row = wc * 64 + n * 16 + l15;
      int p = l4 ^ (row & 3) ^ ((row >> 2) & 3);
      bfr[n] = *(const bf16x8*)&Bsrc[row * 32 + p * 8];
    }
#pragma unroll
    for (int m = 0; m < 4; ++m)
#pragma unroll
      for (int n = 0; n < 4; ++n)
        acc[m][n] = __builtin_amdgcn_mfma_f32_16x16x32_bf16(
            af[m], bfr[n], acc[m][n], 0, 0, 0);
  };

  int NT = K >> 5;        // 16 or 32 (power of 2)
  int NTM = NT - 1;

  STAGE(0, 0);
  STAGE(1, 1);
  STAGE(2, 2);

  for (int t = 0; t < NT; ++t) {
    STAGE((t + 3) & 3, (t + 3) & NTM);  // 16 outstanding after issue
    __builtin_amdgcn_sched_barrier(0);
    asm volatile("s_waitcnt vmcnt(12)" ::: "memory");  // stage t landed (mine)
    __builtin_amdgcn_sched_barrier(0);
    __builtin_amdgcn_s_barrier();                      // ... landed for ALL
    __builtin_amdgcn_sched_barrier(0);
    const u16* Asrc = lds + (t & 3) * 8192;
    COMPUTE(Asrc, Asrc + 4096);
  }
  asm volatile("s_waitcnt vmcnt(0)" ::: "memory");  // drain before endpgm

  long orow0 = (long)by * 128 + wr * 64;
  long ocol0 = (long)bx * 128 + wc * 64;
#pragma unroll
  for (int m = 0; m < 4; ++m) {
#pragma unroll
    for (int n = 0; n < 4; ++n) {
#pragma unroll
      for (int r = 0; r < 4; ++r) {
        long row = orow0 + m * 16 + l4 * 4 + r;
        long col = ocol0 + n * 16 + l15;
        float v = acc[m][n][r] * scale;
        if (bias_mode == 1) v += bias[row];
        else if (bias_mode == 2) v += bias[col];
        long off = (long)z * strideO + row * ldo + col;
        if (residual) v += residual[off];
        if (out_fp32) ((float*)Out)[off] = v;
        else ((u16*)Out)[off] = f2bf(v);
      }
    }
  }
}

// ---------------- softmax over rows of P [rows, S] bf16, in place ----------
__global__ __launch_bounds__(256) void softmax_kernel(u16* __restrict__ P, int S) {
  size_t row = blockIdx.x;
  u16* p = P + row * (size_t)S;
  int tid = threadIdx.x;
  ushort4 u = *(const ushort4*)&p[tid * 4];
  float v0 = bf2f(u.x), v1 = bf2f(u.y), v2 = bf2f(u.z), v3 = bf2f(u.w);
  float m = fmaxf(fmaxf(v0, v1), fmaxf(v2, v3));
  for (int o = 32; o > 0; o >>= 1) m = fmaxf(m, __shfl_xor(m, o));
  __shared__ float redm[4], reds[4];
  int wave = tid >> 6, lane = tid & 63;
  if (lane == 0) redm[wave] = m;
  __syncthreads();
  m = fmaxf(fmaxf(redm[0], redm[1]), fmaxf(redm[2], redm[3]));
  float e0 = __expf(v0 - m), e1 = __expf(v1 - m);
  float e2 = __expf(v2 - m), e3 = __expf(v3 - m);
  float s = e0 + e1 + e2 + e3;
  for (int o = 32; o > 0; o >>= 1) s += __shfl_xor(s, o);
  if (lane == 0) reds[wave] = s;
  __syncthreads();
  s = reds[0] + reds[1] + reds[2] + reds[3];
  float inv = 1.f / s;
  ushort4 o4;
  o4.x = f2bf(e0 * inv); o4.y = f2bf(e1 * inv);
  o4.z = f2bf(e2 * inv); o4.w = f2bf(e3 * inv);
  *(ushort4*)&p[tid * 4] = o4;
}

extern "C" void kernel_launch(void* const* d_in, const int* in_sizes, int n_in,
                              void* d_out, int out_size, void* d_ws, size_t ws_size,
                              hipStream_t stream) {
  const float* x = (const float*)d_in[0];
  const float* gamma = (const float*)d_in[1];
  const float* beta = (const float*)d_in[2];
  const float* wq = (const float*)d_in[3];
  const float* bq = (const float*)d_in[4];
  const float* wk = (const float*)d_in[5];
  const float* bk = (const float*)d_in[6];
  const float* wv = (const float*)d_in[7];
  const float* bv = (const float*)d_in[8];
  const float* wo = (const float*)d_in[9];
  const float* bo = (const float*)d_in[10];

  const int C = 512, S = 1024;
  const int N = in_sizes[0] / (C * S);  // 16
  const long SC = (long)S * C;
  const long S2C = (long)S * 2 * C;
  const long SS = (long)S * S;
  const int CC = C * C;

  char* ws = (char*)d_ws;
  const size_t MB = 1024 * 1024;
  u16* HT = (u16*)(ws + 0 * MB);      // [N,S,C]
  u16* QKT = (u16*)(ws + 16 * MB);    // [N,S,2C]: cols 0..C-1 = Q, C..2C-1 = K
  u16* Vb = (u16*)(ws + 48 * MB);     // [N,C,S]
  u16* P = (u16*)(ws + 64 * MB);      // [N,S,S]
  u16* Wqk = (u16*)(ws + 96 * MB);    // [2C,C]
  u16* Wv = Wqk + 2 * CC;
  u16* Wo = Wv + CC;
  float* bqk = (float*)(Wo + CC);     // [2C]
  u16* H2T = HT;                      // overlay: HT dead after V-GEMM

  cvt_kernel<<<dim3(CC / 1024, 4), 256, 0, stream>>>(wq, wk, wv, wo, Wqk, Wv, Wo, CC);
  biascat_kernel<<<4, 256, 0, stream>>>(bq, bk, bqk, C);
  groupnorm_kernel<<<N * GROUPS, 256, 0, stream>>>(x, gamma, beta, HT, C, S);

  const float scl = 1.0f / sqrtf((float)C);

  // fused Q,K projection: QKT[s][j] = sum_c HT[s][c]*Wqk[j][c] + bqk[j]
  gemm128_kernel<<<dim3((2 * C / 128) * (S / 128) * N), 256, 0, stream>>>(
      HT, C, SC, Wqk, C, 0, QKT, 2 * C, S2C, 0, bqk, 2, 1.f, nullptr, C,
      2 * C / 128, S / 128);
  // V[c][s] = sum_k Wv[c][k]*HT[s][k] + bv[c]
  gemm128_kernel<<<dim3((S / 128) * (C / 128) * N), 256, 0, stream>>>(
      Wv, C, 0, HT, C, SC, Vb, S, SC, 0, bv, 1, 1.f, nullptr, C,
      S / 128, C / 128);
  // P[s][t] = scl * sum_c Q[s][c]*K[t][c]
  gemm128_kernel<<<dim3((S / 128) * (S / 128) * N), 256, 0, stream>>>(
      QKT, 2 * C, S2C, QKT + C, 2 * C, S2C, P, S, SS, 0, nullptr, 0, scl,
      nullptr, C, S / 128, S / 128);
  softmax_kernel<<<N * S, 256, 0, stream>>>(P, S);
  // H2T[s][c] = sum_t P[s][t]*V[c][t]
  gemm128_kernel<<<dim3((C / 128) * (S / 128) * N), 256, 0, stream>>>(
      P, S, SS, Vb, S, SC, H2T, C, SC, 0, nullptr, 0, 1.f, nullptr, S,
      C / 128, S / 128);
  // out[c][s] = x + bo[c] + sum_k Wo[c][k]*H2T[s][k]   (fp32)
  gemm128_kernel<<<dim3((S / 128) * (C / 128) * N), 256, 0, stream>>>(
      Wo, C, 0, H2T, C, SC, d_out, S, SC, 1, bo, 1, 1.f, x, C,
      S / 128, C / 128);
}

// Round 8
// 200.847 us; speedup vs baseline: 1.1307x; 1.1307x over previous
//
#include <hip/hip_runtime.h>

#define GROUPS 32
#define EPS 1e-5f

typedef unsigned short u16;
typedef __bf16 bf16x8 __attribute__((ext_vector_type(8)));
typedef float f32x4 __attribute__((ext_vector_type(4)));

__device__ __forceinline__ u16 f2bf(float f) {
  unsigned x = __builtin_bit_cast(unsigned, f);
  x += 0x7FFFu + ((x >> 16) & 1u);
  return (u16)(x >> 16);
}
__device__ __forceinline__ float bf2f(u16 u) {
  unsigned x = ((unsigned)u) << 16;
  return __builtin_bit_cast(float, x);
}

__device__ __forceinline__ void gload_lds16(const void* g, void* l) {
  __builtin_amdgcn_global_load_lds(
      (const __attribute__((address_space(1))) void*)g,
      (__attribute__((address_space(3))) void*)l, 16, 0, 0);
}

// ---------------- weight fp32 -> bf16 (all 4 weights, one dispatch) --------
__global__ __launch_bounds__(256) void cvt_kernel(
    const float* __restrict__ wq, const float* __restrict__ wk,
    const float* __restrict__ wv, const float* __restrict__ wo,
    u16* __restrict__ Wqk, u16* __restrict__ Wv, u16* __restrict__ Wo,
    int n) {
  int i = (blockIdx.x * 256 + threadIdx.x) * 4;
  if (i >= n) return;
  const float* src;
  u16* dst;
  switch (blockIdx.y) {
    case 0: src = wq; dst = Wqk; break;
    case 1: src = wk; dst = Wqk + n; break;
    case 2: src = wv; dst = Wv; break;
    default: src = wo; dst = Wo; break;
  }
  float4 v = *(const float4*)&src[i];
  ushort4 o;
  o.x = f2bf(v.x); o.y = f2bf(v.y); o.z = f2bf(v.z); o.w = f2bf(v.w);
  *(ushort4*)&dst[i] = o;
}

// ---------------- bias concat bq||bk -> fp32[1024] ----------------
__global__ __launch_bounds__(256) void biascat_kernel(
    const float* __restrict__ bq, const float* __restrict__ bk,
    float* __restrict__ bqk, int C) {
  int i = blockIdx.x * 256 + threadIdx.x;
  if (i < C) bqk[i] = bq[i];
  else if (i < 2 * C) bqk[i] = bk[i - C];
}

// ---------------- GroupNorm -> HT [N, S, C] bf16 ----------------
__global__ __launch_bounds__(256) void groupnorm_kernel(
    const float* __restrict__ x, const float* __restrict__ gamma,
    const float* __restrict__ beta, u16* __restrict__ HT, int C, int S) {
  const int cpg = C / GROUPS;  // 16
  __shared__ float xs[16 * 1024];  // 64 KB, layout == global slab [c][sp]
  __shared__ float rs[4], rss[4];
  int n = blockIdx.x / GROUPS;
  int g = blockIdx.x % GROUPS;
  const float* xb = x + ((size_t)n * C + (size_t)g * cpg) * S;
  int tid = threadIdx.x;
  int cnt = cpg * S;  // 16384
  float s = 0.f, ss = 0.f;
  for (int i = tid * 4; i < cnt; i += 256 * 4) {
    float4 v = *(const float4*)&xb[i];
    *(float4*)&xs[i] = v;
    s += v.x + v.y + v.z + v.w;
    ss += v.x * v.x + v.y * v.y + v.z * v.z + v.w * v.w;
  }
  for (int o = 32; o > 0; o >>= 1) {
    s += __shfl_xor(s, o);
    ss += __shfl_xor(ss, o);
  }
  int wave = tid >> 6, lane = tid & 63;
  if (lane == 0) { rs[wave] = s; rss[wave] = ss; }
  __syncthreads();
  float S1 = rs[0] + rs[1] + rs[2] + rs[3];
  float S2 = rss[0] + rss[1] + rss[2] + rss[3];
  float mean = S1 / (float)cnt;
  float var = S2 / (float)cnt - mean * mean;
  float rstd = rsqrtf(var + EPS);
  float gm[16], bt[16];
#pragma unroll
  for (int c = 0; c < 16; ++c) {
    float gmv = gamma[g * cpg + c] * rstd;
    gm[c] = gmv;
    bt[c] = beta[g * cpg + c] - mean * gmv;
  }
  for (int i = 0; i < S; i += 256) {
    int sp = i + tid;
    u16 outv[16];
#pragma unroll
    for (int c = 0; c < 16; ++c) {
      float h = xs[c * 1024 + sp] * gm[c] + bt[c];
      outv[c] = f2bf(h);
    }
    u16* dst = HT + ((size_t)n * S + sp) * C + g * cpg;
    *(int4*)dst = *(int4*)&outv[0];
    *(int4*)&dst[8] = *(int4*)&outv[8];
  }
}

// =================== 256x128x32 2-phase GEMM (8 waves) =====================
// Out[m][n] = scale*sum_k A[m][k]*B[n][k] (+bias/residual)
// Round-5 schedule (best measured): per K-tile { STAGE(next buf) first;
// compute; vmcnt(0); s_barrier }. 48 KB LDS dbuf + VGPR<=128 -> 2 blocks/CU.
// BM=256 halves A-panel staging vs 128^2 (panel bytes prop 1/BM+1/BN).
// LDS layout: two consecutive rows interleave into one 64-elem line;
// 16B granule at (line l, phys p) holds global (row = 2l + (q>>2),
// kslot = q&3) with q = p ^ (l&7).  Read: p = ((R&1)*4+kg) ^ ((R>>1)&7).
// This reproduces the BK=64 8-slot geometry that measured 0 conflicts.
__global__ __launch_bounds__(512, 4) void gemm256x128_kernel(
    const u16* __restrict__ A, long lda, long strideA,
    const u16* __restrict__ B, long ldb, long strideB,
    void* __restrict__ Out, long ldo, long strideO, int out_fp32,
    const float* __restrict__ bias, int bias_mode,  // 0 none, 1 row, 2 col
    float scale, const float* __restrict__ residual, int K, int nbx, int nby) {
  __shared__ u16 lds[24576];  // 48 KiB
  u16* As0 = lds;             // 256x32 = 8192 u16 (1024 granules)
  u16* Bs0 = lds + 8192;      // 128x32 = 4096 u16 (512 granules)
  u16* As1 = lds + 12288;
  u16* Bs1 = lds + 20480;

  int tid = threadIdx.x;
  int wave = tid >> 6, lane = tid & 63;
  int wr = wave >> 1, wc = wave & 1;   // 4 x 2 wave grid, 64x64 per wave
  int l15 = lane & 15, l4 = lane >> 4;

  int nwg = gridDim.x;
  int orig = blockIdx.x;
  int swz = ((nwg & 7) == 0) ? (orig & 7) * (nwg >> 3) + (orig >> 3) : orig;
  int tilesPB = nbx * nby;
  int z = swz / tilesPB, rem = swz % tilesPB;
  int bx = rem % nbx, by = rem / nbx;

  const u16* Ab = A + (long)z * strideA + (long)by * 256 * lda;
  const u16* Bb = B + (long)z * strideB + (long)bx * 128 * ldb;

  // stage one 256x32 A tile + 128x32 B tile (1536 granules, 3/thread)
  auto STAGE = [&](u16* Ad, u16* Bd, int kt) {
#pragma unroll
    for (int i = 0; i < 2; ++i) {       // A granules
      int c = i * 512 + tid;            // 0..1023
      int l = c >> 3, p = c & 7;
      int q = p ^ (l & 7);
      int row = 2 * l + (q >> 2);
      long koff = (long)kt * 32 + (q & 3) * 8;
      int lbase = (i * 512 + wave * 64) * 8;
      gload_lds16(Ab + (long)row * lda + koff, Ad + lbase);
    }
    {                                   // B granules
      int c = tid;                      // 0..511
      int l = c >> 3, p = c & 7;
      int q = p ^ (l & 7);
      int row = 2 * l + (q >> 2);
      long koff = (long)kt * 32 + (q & 3) * 8;
      int lbase = (wave * 64) * 8;
      gload_lds16(Bb + (long)row * ldb + koff, Bd + lbase);
    }
  };

  f32x4 acc[4][4] = {};

  auto COMPUTE = [&](const u16* Asrc, const u16* Bsrc) {
    bf16x8 af[4], bfr[4];
#pragma unroll
    for (int m = 0; m < 4; ++m) {
      int R = wr * 64 + m * 16 + l15;
      int line = R >> 1;
      int p = ((R & 1) * 4 + l4) ^ (line & 7);
      af[m] = *(const bf16x8*)&Asrc[line * 64 + p * 8];
    }
#pragma unroll
    for (int n = 0; n < 4; ++n) {
      int R = wc * 64 + n * 16 + l15;
      int line = R >> 1;
      int p = ((R & 1) * 4 + l4) ^ (line & 7);
      bfr[n] = *(const bf16x8*)&Bsrc[line * 64 + p * 8];
    }
#pragma unroll
    for (int m = 0; m < 4; ++m)
#pragma unroll
      for (int n = 0; n < 4; ++n)
        acc[m][n] = __builtin_amdgcn_mfma_f32_16x16x32_bf16(
            af[m], bfr[n], acc[m][n], 0, 0, 0);
  };

  int NT = K >> 5;
  u16 *Ar = As0, *Br = Bs0, *Aw = As1, *Bw = Bs1;

  STAGE(Ar, Br, 0);
  asm volatile("s_waitcnt vmcnt(0)" ::: "memory");
  __builtin_amdgcn_sched_barrier(0);
  __builtin_amdgcn_s_barrier();
  __builtin_amdgcn_sched_barrier(0);

  for (int t = 0; t < NT - 1; ++t) {
    STAGE(Aw, Bw, t + 1);       // issue next-tile loads first
    COMPUTE(Ar, Br);            // they fly under ds_read + MFMA
    asm volatile("s_waitcnt vmcnt(0)" ::: "memory");
    __builtin_amdgcn_sched_barrier(0);
    __builtin_amdgcn_s_barrier();
    __builtin_amdgcn_sched_barrier(0);
    u16* tp;
    tp = Ar; Ar = Aw; Aw = tp;
    tp = Br; Br = Bw; Bw = tp;
  }
  COMPUTE(Ar, Br);

  long orow0 = (long)by * 256 + wr * 64;
  long ocol0 = (long)bx * 128 + wc * 64;
#pragma unroll
  for (int m = 0; m < 4; ++m) {
#pragma unroll
    for (int n = 0; n < 4; ++n) {
#pragma unroll
      for (int r = 0; r < 4; ++r) {
        long row = orow0 + m * 16 + l4 * 4 + r;
        long col = ocol0 + n * 16 + l15;
        float v = acc[m][n][r] * scale;
        if (bias_mode == 1) v += bias[row];
        else if (bias_mode == 2) v += bias[col];
        long off = (long)z * strideO + row * ldo + col;
        if (residual) v += residual[off];
        if (out_fp32) ((float*)Out)[off] = v;
        else ((u16*)Out)[off] = f2bf(v);
      }
    }
  }
}

// ---------------- softmax over rows of P [rows, S] bf16, in place ----------
__global__ __launch_bounds__(256) void softmax_kernel(u16* __restrict__ P, int S) {
  size_t row = blockIdx.x;
  u16* p = P + row * (size_t)S;
  int tid = threadIdx.x;
  ushort4 u = *(const ushort4*)&p[tid * 4];
  float v0 = bf2f(u.x), v1 = bf2f(u.y), v2 = bf2f(u.z), v3 = bf2f(u.w);
  float m = fmaxf(fmaxf(v0, v1), fmaxf(v2, v3));
  for (int o = 32; o > 0; o >>= 1) m = fmaxf(m, __shfl_xor(m, o));
  __shared__ float redm[4], reds[4];
  int wave = tid >> 6, lane = tid & 63;
  if (lane == 0) redm[wave] = m;
  __syncthreads();
  m = fmaxf(fmaxf(redm[0], redm[1]), fmaxf(redm[2], redm[3]));
  float e0 = __expf(v0 - m), e1 = __expf(v1 - m);
  float e2 = __expf(v2 - m), e3 = __expf(v3 - m);
  float s = e0 + e1 + e2 + e3;
  for (int o = 32; o > 0; o >>= 1) s += __shfl_xor(s, o);
  if (lane == 0) reds[wave] = s;
  __syncthreads();
  s = reds[0] + reds[1] + reds[2] + reds[3];
  float inv = 1.f / s;
  ushort4 o4;
  o4.x = f2bf(e0 * inv); o4.y = f2bf(e1 * inv);
  o4.z = f2bf(e2 * inv); o4.w = f2bf(e3 * inv);
  *(ushort4*)&p[tid * 4] = o4;
}

extern "C" void kernel_launch(void* const* d_in, const int* in_sizes, int n_in,
                              void* d_out, int out_size, void* d_ws, size_t ws_size,
                              hipStream_t stream) {
  const float* x = (const float*)d_in[0];
  const float* gamma = (const float*)d_in[1];
  const float* beta = (const float*)d_in[2];
  const float* wq = (const float*)d_in[3];
  const float* bq = (const float*)d_in[4];
  const float* wk = (const float*)d_in[5];
  const float* bk = (const float*)d_in[6];
  const float* wv = (const float*)d_in[7];
  const float* bv = (const float*)d_in[8];
  const float* wo = (const float*)d_in[9];
  const float* bo = (const float*)d_in[10];

  const int C = 512, S = 1024;
  const int N = in_sizes[0] / (C * S);  // 16
  const long SC = (long)S * C;
  const long S2C = (long)S * 2 * C;
  const long SS = (long)S * S;
  const int CC = C * C;

  char* ws = (char*)d_ws;
  const size_t MB = 1024 * 1024;
  u16* HT = (u16*)(ws + 0 * MB);      // [N,S,C]
  u16* QKT = (u16*)(ws + 16 * MB);    // [N,S,2C]: cols 0..C-1 = Q, C..2C-1 = K
  u16* Vb = (u16*)(ws + 48 * MB);     // [N,C,S]
  u16* P = (u16*)(ws + 64 * MB);      // [N,S,S]
  u16* Wqk = (u16*)(ws + 96 * MB);    // [2C,C]
  u16* Wv = Wqk + 2 * CC;
  u16* Wo = Wv + CC;
  float* bqk = (float*)(Wo + CC);     // [2C]
  u16* H2T = HT;                      // overlay: HT dead after V-GEMM

  cvt_kernel<<<dim3(CC / 1024, 4), 256, 0, stream>>>(wq, wk, wv, wo, Wqk, Wv, Wo, CC);
  biascat_kernel<<<4, 256, 0, stream>>>(bq, bk, bqk, C);
  groupnorm_kernel<<<N * GROUPS, 256, 0, stream>>>(x, gamma, beta, HT, C, S);

  const float scl = 1.0f / sqrtf((float)C);

  // fused Q,K projection: QKT[s][j] = sum_c HT[s][c]*Wqk[j][c] + bqk[j]
  gemm256x128_kernel<<<dim3((S / 256) * (2 * C / 128) * N), 512, 0, stream>>>(
      HT, C, SC, Wqk, C, 0, QKT, 2 * C, S2C, 0, bqk, 2, 1.f, nullptr, C,
      2 * C / 128, S / 256);
  // V[c][s] = sum_k Wv[c][k]*HT[s][k] + bv[c]
  gemm256x128_kernel<<<dim3((C / 256) * (S / 128) * N), 512, 0, stream>>>(
      Wv, C, 0, HT, C, SC, Vb, S, SC, 0, bv, 1, 1.f, nullptr, C,
      S / 128, C / 256);
  // P[s][t] = scl * sum_c Q[s][c]*K[t][c]
  gemm256x128_kernel<<<dim3((S / 256) * (S / 128) * N), 512, 0, stream>>>(
      QKT, 2 * C, S2C, QKT + C, 2 * C, S2C, P, S, SS, 0, nullptr, 0, scl,
      nullptr, C, S / 128, S / 256);
  softmax_kernel<<<N * S, 256, 0, stream>>>(P, S);
  // H2T[s][c] = sum_t P[s][t]*V[c][t]
  gemm256x128_kernel<<<dim3((S / 256) * (C / 128) * N), 512, 0, stream>>>(
      P, S, SS, Vb, S, SC, H2T, C, SC, 0, nullptr, 0, 1.f, nullptr, S,
      C / 128, S / 256);
  // out[c][s] = x + bo[c] + sum_k Wo[c][k]*H2T[s][k]   (fp32)
  gemm256x128_kernel<<<dim3((C / 256) * (S / 128) * N), 512, 0, stream>>>(
      Wo, C, 0, H2T, C, SC, d_out, S, SC, 1, bo, 1, 1.f, x, C,
      S / 128, C / 256);
}